// Round 2
// baseline (468.145 us; speedup 1.0000x reference)
//
#include <hip/hip_runtime.h>
#include <hip/hip_bf16.h>

#define BT   16
#define IH   48
#define IW   48
#define CH   64
#define NH   8
#define HD   8
#define KS   7
#define KK   49
#define NPIX (BT*IH*IW)          /* 36864 */
#define QKVC 192
#define LN_EPS 1e-5f
#define QSCALE 0.35355339059327373f

__device__ __forceinline__ float bflo(unsigned u) { union { unsigned i; float f; } v; v.i = u << 16; return v.f; }
__device__ __forceinline__ float bfhi(unsigned u) { union { unsigned i; float f; } v; v.i = u & 0xffff0000u; return v.f; }

// 8 consecutive bf16 -> 8 floats (16B aligned load)
__device__ __forceinline__ void ld8bf(const __hip_bfloat16* p, float f[8]) {
    uint4 u = *reinterpret_cast<const uint4*>(p);
    f[0] = bflo(u.x); f[1] = bfhi(u.x);
    f[2] = bflo(u.y); f[3] = bfhi(u.y);
    f[4] = bflo(u.z); f[5] = bfhi(u.z);
    f[6] = bflo(u.w); f[7] = bfhi(u.w);
}

// ---------------- K1: per-pixel QKV projection (64 -> 192), q pre-scaled ----
__global__ __launch_bounds__(192) void qkv_kernel(
        const float* __restrict__ x,
        const float* __restrict__ w,
        const float* __restrict__ b,
        __hip_bfloat16* __restrict__ qkv) {
    __shared__ float xs[CH];
    const int pix = blockIdx.x;
    const int t = threadIdx.x;            // 0..191 = output channel
    if (t < CH) xs[t] = x[(size_t)pix * CH + t];
    __syncthreads();
    float acc = b[t];
    const float4* wr = reinterpret_cast<const float4*>(w + t * CH);
    #pragma unroll
    for (int c4 = 0; c4 < CH / 4; ++c4) {
        float4 u = wr[c4];
        acc += xs[4 * c4] * u.x + xs[4 * c4 + 1] * u.y
             + xs[4 * c4 + 2] * u.z + xs[4 * c4 + 3] * u.w;
    }
    if (t < CH) acc *= QSCALE;            // q rows get the 1/sqrt(hd) scale baked in
    qkv[(size_t)pix * QKVC + t] = __float2bfloat16(acc);
}

// ---------------- K2: neighborhood attention, 1 thread = (pixel, head) ------
__global__ __launch_bounds__(256) void attn_kernel(
        const __hip_bfloat16* __restrict__ qkv,
        const float* __restrict__ rpb,
        float* __restrict__ aout) {
    const int gid = blockIdx.x * blockDim.x + threadIdx.x;
    if (gid >= NPIX * NH) return;
    const int h = gid & (NH - 1);
    const int pix = gid >> 3;
    const int n = pix / (IH * IW);
    const int rem = pix - n * (IH * IW);
    const int i = rem / IW;
    const int j = rem - i * IW;

    float qv[HD];
    ld8bf(qkv + (size_t)pix * QKVC + h * HD, qv);

    int si = i - 3; si = si < 0 ? 0 : (si > IH - KS ? IH - KS : si);
    int sj = j - 3; sj = sj < 0 ? 0 : (sj > IW - KS ? IW - KS : sj);

    const float* rp = rpb + h * (2 * KS - 1) * (2 * KS - 1);

    float s[KK];
    float m = -1e30f;
    for (int p = 0; p < KS; ++p) {
        const int ki = si + p;
        const int ri = ki - i + (KS - 1);
        const __hip_bfloat16* krow = qkv + ((size_t)(n * IH * IW + ki * IW)) * QKVC;
        #pragma unroll
        for (int qq = 0; qq < KS; ++qq) {
            const int kj = sj + qq;
            float kf[HD];
            ld8bf(krow + kj * QKVC + CH + h * HD, kf);
            float acc = rp[ri * (2 * KS - 1) + (kj - j + (KS - 1))];
            #pragma unroll
            for (int d = 0; d < HD; ++d) acc += qv[d] * kf[d];
            s[p * KS + qq] = acc;
            m = fmaxf(m, acc);
        }
    }
    float sum = 0.f;
    #pragma unroll
    for (int e = 0; e < KK; ++e) { float wv = __expf(s[e] - m); s[e] = wv; sum += wv; }
    const float inv = 1.f / sum;

    float acc[HD];
    #pragma unroll
    for (int d = 0; d < HD; ++d) acc[d] = 0.f;
    for (int p = 0; p < KS; ++p) {
        const int ki = si + p;
        const __hip_bfloat16* vrow = qkv + ((size_t)(n * IH * IW + ki * IW)) * QKVC;
        #pragma unroll
        for (int qq = 0; qq < KS; ++qq) {
            const int kj = sj + qq;
            float vf[HD];
            ld8bf(vrow + kj * QKVC + 2 * CH + h * HD, vf);
            const float wv = s[p * KS + qq] * inv;
            #pragma unroll
            for (int d = 0; d < HD; ++d) acc[d] += wv * vf[d];
        }
    }
    float* op = aout + (size_t)pix * CH + h * HD;
    #pragma unroll
    for (int d = 0; d < HD; ++d) op[d] = acc[d];
}

// ---------------- K3: out-projection (64x64) + LayerNorm, 1 wave / pixel ----
__global__ __launch_bounds__(64) void proj_ln_kernel(
        const float* __restrict__ aout,
        const float* __restrict__ pw,
        const float* __restrict__ pb,
        const float* __restrict__ g,
        const float* __restrict__ beta,
        float* __restrict__ out) {
    const int pix = blockIdx.x;
    const int o = threadIdx.x;            // 0..63 = output channel
    __shared__ float xs[CH];
    xs[o] = aout[(size_t)pix * CH + o];
    __syncthreads();
    float acc = pb[o];
    const float4* wr = reinterpret_cast<const float4*>(pw + o * CH);
    #pragma unroll
    for (int c4 = 0; c4 < CH / 4; ++c4) {
        float4 u = wr[c4];
        acc += xs[4 * c4] * u.x + xs[4 * c4 + 1] * u.y
             + xs[4 * c4 + 2] * u.z + xs[4 * c4 + 3] * u.w;
    }
    // LayerNorm across the 64-lane wave
    float sum = acc;
    #pragma unroll
    for (int off = 32; off > 0; off >>= 1) sum += __shfl_xor(sum, off, 64);
    const float mu = sum * (1.f / 64.f);
    const float d = acc - mu;
    float vs = d * d;
    #pragma unroll
    for (int off = 32; off > 0; off >>= 1) vs += __shfl_xor(vs, off, 64);
    const float var = vs * (1.f / 64.f);
    const float y = d * rsqrtf(var + LN_EPS) * g[o] + beta[o];
    out[(size_t)pix * CH + o] = y;
}

extern "C" void kernel_launch(void* const* d_in, const int* in_sizes, int n_in,
                              void* d_out, int out_size, void* d_ws, size_t ws_size,
                              hipStream_t stream) {
    const float* x      = (const float*)d_in[0];
    const float* qkv_w  = (const float*)d_in[1];
    const float* qkv_b  = (const float*)d_in[2];
    const float* proj_w = (const float*)d_in[3];
    const float* proj_b = (const float*)d_in[4];
    const float* rpb    = (const float*)d_in[5];
    const float* ln_g   = (const float*)d_in[6];
    const float* ln_b   = (const float*)d_in[7];
    float* out = (float*)d_out;

    // workspace: [qkv bf16: NPIX*192*2 = 14,155,776 B][attn_out fp32: NPIX*64*4 = 9,437,184 B]
    __hip_bfloat16* qkv = (__hip_bfloat16*)d_ws;
    float* aout = (float*)((char*)d_ws + (size_t)NPIX * QKVC * 2);

    qkv_kernel<<<NPIX, 192, 0, stream>>>(x, qkv_w, qkv_b, qkv);
    attn_kernel<<<(NPIX * NH + 255) / 256, 256, 0, stream>>>(qkv, rpb, aout);
    proj_ln_kernel<<<NPIX, 64, 0, stream>>>(aout, proj_w, proj_b, ln_g, ln_b, out);
}

// Round 3
// 241.700 us; speedup vs baseline: 1.9369x; 1.9369x over previous
//
#include <hip/hip_runtime.h>
#include <hip/hip_bf16.h>

#define BT   16
#define IH   48
#define IW   48
#define CH   64
#define NH   8
#define HD   8
#define KS   7
#define KK   49
#define NPIX (BT*IH*IW)          /* 36864 */
#define QKVC 192
#define LN_EPS 1e-5f
#define QSCALE 0.35355339059327373f

typedef __bf16 bf16_t;
typedef bf16_t bf16x8 __attribute__((ext_vector_type(8)));
typedef float  f32x4  __attribute__((ext_vector_type(4)));

__device__ __forceinline__ float bflo(unsigned u) { union { unsigned i; float f; } v; v.i = u << 16; return v.f; }
__device__ __forceinline__ float bfhi(unsigned u) { union { unsigned i; float f; } v; v.i = u & 0xffff0000u; return v.f; }

// 8 consecutive bf16 -> 8 floats (16B aligned load)
__device__ __forceinline__ void ld8bf(const __hip_bfloat16* p, float f[8]) {
    uint4 u = *reinterpret_cast<const uint4*>(p);
    f[0] = bflo(u.x); f[1] = bfhi(u.x);
    f[2] = bflo(u.y); f[3] = bfhi(u.y);
    f[4] = bflo(u.z); f[5] = bfhi(u.z);
    f[6] = bflo(u.w); f[7] = bfhi(u.w);
}

__device__ __forceinline__ bf16x8 pack_bf16x8(float4 lo, float4 hi) {
    bf16x8 r;
    r[0] = (bf16_t)lo.x; r[1] = (bf16_t)lo.y; r[2] = (bf16_t)lo.z; r[3] = (bf16_t)lo.w;
    r[4] = (bf16_t)hi.x; r[5] = (bf16_t)hi.y; r[6] = (bf16_t)hi.z; r[7] = (bf16_t)hi.w;
    return r;
}

// ---------------- K1: QKV projection as MFMA GEMM -------------------------
// M=NPIX, N=192, K=64.  One wave = one 16-pixel m-tile x four 16-wide n-tiles.
// A frag: lane holds x[mtile+(l&15)][kg*8..+7]   (kg = l>>4)
// B frag: lane holds w[nt*16+(l&15)][kg*8..+7]   (w row-major [oc][64])
// D:      col = l&15, row = kg*4 + reg           (m89-verified layout)
__global__ __launch_bounds__(256) void qkv_kernel(
        const float* __restrict__ x,
        const float* __restrict__ w,
        const float* __restrict__ b,
        __hip_bfloat16* __restrict__ qkv) {
    const int wave  = (blockIdx.x * blockDim.x + threadIdx.x) >> 6;  // 0..6911
    const int ngrp  = wave % 3;          // 4 n-tiles per wave
    const int mtile = wave / 3;          // 0..2303
    const int l  = threadIdx.x & 63;
    const int m  = l & 15;
    const int kg = l >> 4;

    const float* xr = x + (size_t)(mtile * 16 + m) * CH + kg * 8;
    const float4 u0 = *(const float4*)(xr);
    const float4 u1 = *(const float4*)(xr + 4);
    const float4 u2 = *(const float4*)(xr + 32);
    const float4 u3 = *(const float4*)(xr + 36);
    const bf16x8 a0 = pack_bf16x8(u0, u1);   // k = 0..31 slice
    const bf16x8 a1 = pack_bf16x8(u2, u3);   // k = 32..63 slice

    #pragma unroll
    for (int t = 0; t < 4; ++t) {
        const int nt = ngrp * 4 + t;
        const int oc = nt * 16 + m;
        const float* wr_ = w + (size_t)oc * CH + kg * 8;
        const float4 w0 = *(const float4*)(wr_);
        const float4 w1 = *(const float4*)(wr_ + 4);
        const float4 w2 = *(const float4*)(wr_ + 32);
        const float4 w3 = *(const float4*)(wr_ + 36);
        const bf16x8 b0 = pack_bf16x8(w0, w1);
        const bf16x8 b1 = pack_bf16x8(w2, w3);
        f32x4 acc = {0.f, 0.f, 0.f, 0.f};
        acc = __builtin_amdgcn_mfma_f32_16x16x32_bf16(a0, b0, acc, 0, 0, 0);
        acc = __builtin_amdgcn_mfma_f32_16x16x32_bf16(a1, b1, acc, 0, 0, 0);
        const float bias  = b[oc];
        const float scale = (oc < CH) ? QSCALE : 1.f;   // q gets 1/sqrt(hd)
        #pragma unroll
        for (int r = 0; r < 4; ++r) {
            const int pix = mtile * 16 + kg * 4 + r;
            qkv[(size_t)pix * QKVC + oc] = __float2bfloat16((acc[r] + bias) * scale);
        }
    }
}

// ---------------- K2: neighborhood attention, 1 thread = (pixel, head) ------
__global__ __launch_bounds__(256) void attn_kernel(
        const __hip_bfloat16* __restrict__ qkv,
        const float* __restrict__ rpb,
        __hip_bfloat16* __restrict__ aout) {
    const int gid = blockIdx.x * blockDim.x + threadIdx.x;
    if (gid >= NPIX * NH) return;
    const int h = gid & (NH - 1);
    const int pix = gid >> 3;
    const int n = pix / (IH * IW);
    const int rem = pix - n * (IH * IW);
    const int i = rem / IW;
    const int j = rem - i * IW;

    float qv[HD];
    ld8bf(qkv + (size_t)pix * QKVC + h * HD, qv);

    int si = i - 3; si = si < 0 ? 0 : (si > IH - KS ? IH - KS : si);
    int sj = j - 3; sj = sj < 0 ? 0 : (sj > IW - KS ? IW - KS : sj);

    const float* rp = rpb + h * (2 * KS - 1) * (2 * KS - 1);

    float s[KK];                       // fully-static indexing -> stays in VGPRs
    float m = -1e30f;
    #pragma unroll
    for (int p = 0; p < KS; ++p) {
        const int ki = si + p;
        const int ri = ki - i + (KS - 1);
        const __hip_bfloat16* krow = qkv + ((size_t)(n * IH * IW + ki * IW)) * QKVC;
        #pragma unroll
        for (int qq = 0; qq < KS; ++qq) {
            const int kj = sj + qq;
            float kf[HD];
            ld8bf(krow + kj * QKVC + CH + h * HD, kf);
            float acc = rp[ri * (2 * KS - 1) + (kj - j + (KS - 1))];
            #pragma unroll
            for (int d = 0; d < HD; ++d) acc += qv[d] * kf[d];
            s[p * KS + qq] = acc;
            m = fmaxf(m, acc);
        }
    }
    float sum = 0.f;
    #pragma unroll
    for (int e = 0; e < KK; ++e) { float wv = __expf(s[e] - m); s[e] = wv; sum += wv; }
    const float inv = 1.f / sum;

    float acc[HD];
    #pragma unroll
    for (int d = 0; d < HD; ++d) acc[d] = 0.f;
    #pragma unroll
    for (int p = 0; p < KS; ++p) {
        const int ki = si + p;
        const __hip_bfloat16* vrow = qkv + ((size_t)(n * IH * IW + ki * IW)) * QKVC;
        #pragma unroll
        for (int qq = 0; qq < KS; ++qq) {
            const int kj = sj + qq;
            float vf[HD];
            ld8bf(vrow + kj * QKVC + 2 * CH + h * HD, vf);
            const float wv = s[p * KS + qq] * inv;
            #pragma unroll
            for (int d = 0; d < HD; ++d) acc[d] += wv * vf[d];
        }
    }
    union { uint4 u; __hip_bfloat16 hh[8]; } pk;
    #pragma unroll
    for (int d = 0; d < HD; ++d) pk.hh[d] = __float2bfloat16(acc[d]);
    *reinterpret_cast<uint4*>(aout + (size_t)pix * CH + h * HD) = pk.u;
}

// ---------------- K3: out-projection MFMA + fused LayerNorm -----------------
// One wave = 16 pixels x all 64 channels (4 n-tiles). LN reduced with shuffles
// across the 16 lanes of each kg-group (masks 1,2,4,8 stay inside the group).
__global__ __launch_bounds__(256) void proj_ln_kernel(
        const __hip_bfloat16* __restrict__ aout,
        const float* __restrict__ pw,
        const float* __restrict__ pb,
        const float* __restrict__ g,
        const float* __restrict__ beta,
        float* __restrict__ out) {
    const int mtile = (blockIdx.x * blockDim.x + threadIdx.x) >> 6;  // 0..2303
    const int l  = threadIdx.x & 63;
    const int m  = l & 15;
    const int kg = l >> 6 ? 0 : (l >> 4);   // l>>4, kept simple below
    const int kgg = l >> 4;

    const __hip_bfloat16* ar = aout + (size_t)(mtile * 16 + m) * CH + kgg * 8;
    const bf16x8 a0 = *reinterpret_cast<const bf16x8*>(ar);
    const bf16x8 a1 = *reinterpret_cast<const bf16x8*>(ar + 32);

    float val[4][4];
    #pragma unroll
    for (int nt = 0; nt < 4; ++nt) {
        const int ch = nt * 16 + m;
        const float* wr_ = pw + (size_t)ch * CH + kgg * 8;
        const float4 w0 = *(const float4*)(wr_);
        const float4 w1 = *(const float4*)(wr_ + 4);
        const float4 w2 = *(const float4*)(wr_ + 32);
        const float4 w3 = *(const float4*)(wr_ + 36);
        const bf16x8 b0 = pack_bf16x8(w0, w1);
        const bf16x8 b1 = pack_bf16x8(w2, w3);
        f32x4 acc = {0.f, 0.f, 0.f, 0.f};
        acc = __builtin_amdgcn_mfma_f32_16x16x32_bf16(a0, b0, acc, 0, 0, 0);
        acc = __builtin_amdgcn_mfma_f32_16x16x32_bf16(a1, b1, acc, 0, 0, 0);
        const float bias = pb[ch];
        #pragma unroll
        for (int r = 0; r < 4; ++r) val[nt][r] = acc[r] + bias;
    }

    // mean over 64 channels per row (row = kgg*4 + r)
    float sm[4];
    #pragma unroll
    for (int r = 0; r < 4; ++r) sm[r] = val[0][r] + val[1][r] + val[2][r] + val[3][r];
    #pragma unroll
    for (int mask = 1; mask <= 8; mask <<= 1) {
        #pragma unroll
        for (int r = 0; r < 4; ++r) sm[r] += __shfl_xor(sm[r], mask, 64);
    }
    float mu[4];
    #pragma unroll
    for (int r = 0; r < 4; ++r) mu[r] = sm[r] * (1.f / 64.f);

    float qs[4];
    #pragma unroll
    for (int r = 0; r < 4; ++r) {
        float a = val[0][r] - mu[r], bq = val[1][r] - mu[r];
        float c = val[2][r] - mu[r], d = val[3][r] - mu[r];
        qs[r] = a * a + bq * bq + c * c + d * d;
    }
    #pragma unroll
    for (int mask = 1; mask <= 8; mask <<= 1) {
        #pragma unroll
        for (int r = 0; r < 4; ++r) qs[r] += __shfl_xor(qs[r], mask, 64);
    }
    float rs[4];
    #pragma unroll
    for (int r = 0; r < 4; ++r) rs[r] = rsqrtf(qs[r] * (1.f / 64.f) + LN_EPS);

    #pragma unroll
    for (int nt = 0; nt < 4; ++nt) {
        const int ch = nt * 16 + m;
        const float gg = g[ch], bb = beta[ch];
        #pragma unroll
        for (int r = 0; r < 4; ++r) {
            const int pix = mtile * 16 + kgg * 4 + r;
            out[(size_t)pix * CH + ch] = (val[nt][r] - mu[r]) * rs[r] * gg + bb;
        }
    }
    (void)kg;
}

extern "C" void kernel_launch(void* const* d_in, const int* in_sizes, int n_in,
                              void* d_out, int out_size, void* d_ws, size_t ws_size,
                              hipStream_t stream) {
    const float* x      = (const float*)d_in[0];
    const float* qkv_w  = (const float*)d_in[1];
    const float* qkv_b  = (const float*)d_in[2];
    const float* proj_w = (const float*)d_in[3];
    const float* proj_b = (const float*)d_in[4];
    const float* rpb    = (const float*)d_in[5];
    const float* ln_g   = (const float*)d_in[6];
    const float* ln_b   = (const float*)d_in[7];
    float* out = (float*)d_out;

    // ws: [qkv bf16: NPIX*192*2 = 14,155,776 B][attn_out bf16: NPIX*64*2 = 4,718,592 B]
    __hip_bfloat16* qkv  = (__hip_bfloat16*)d_ws;
    __hip_bfloat16* aout = (__hip_bfloat16*)((char*)d_ws + (size_t)NPIX * QKVC * 2);

    // K1: 2304 m-tiles x 3 n-groups = 6912 waves = 1728 blocks of 256
    qkv_kernel<<<1728, 256, 0, stream>>>(x, qkv_w, qkv_b, qkv);
    // K2: 294912 threads
    attn_kernel<<<(NPIX * NH) / 256, 256, 0, stream>>>(qkv, rpb, aout);
    // K3: 2304 waves = 576 blocks of 256
    proj_ln_kernel<<<576, 256, 0, stream>>>(aout, proj_w, proj_b, ln_g, ln_b, out);
}

// Round 4
// 140.287 us; speedup vs baseline: 3.3371x; 1.7229x over previous
//
#include <hip/hip_runtime.h>
#include <hip/hip_bf16.h>

#define BT   16
#define IH   48
#define IW   48
#define CH   64
#define NH   8
#define HD   8
#define KS   7
#define KK   49
#define NPIX (BT*IH*IW)          /* 36864 */
#define QKVC 192
#define LN_EPS 1e-5f
#define QSCALE 0.35355339059327373f

typedef __bf16 bf16_t;
typedef bf16_t bf16x8 __attribute__((ext_vector_type(8)));
typedef float  f32x4  __attribute__((ext_vector_type(4)));

__device__ __forceinline__ float bflo(unsigned u) { union { unsigned i; float f; } v; v.i = u << 16; return v.f; }
__device__ __forceinline__ float bfhi(unsigned u) { union { unsigned i; float f; } v; v.i = u & 0xffff0000u; return v.f; }

// 8 consecutive bf16 -> 8 floats (16B aligned load)
__device__ __forceinline__ void ld8bf(const __hip_bfloat16* p, float f[8]) {
    uint4 u = *reinterpret_cast<const uint4*>(p);
    f[0] = bflo(u.x); f[1] = bfhi(u.x);
    f[2] = bflo(u.y); f[3] = bfhi(u.y);
    f[4] = bflo(u.z); f[5] = bfhi(u.z);
    f[6] = bflo(u.w); f[7] = bfhi(u.w);
}

__device__ __forceinline__ bf16x8 pack_bf16x8(float4 lo, float4 hi) {
    bf16x8 r;
    r[0] = (bf16_t)lo.x; r[1] = (bf16_t)lo.y; r[2] = (bf16_t)lo.z; r[3] = (bf16_t)lo.w;
    r[4] = (bf16_t)hi.x; r[5] = (bf16_t)hi.y; r[6] = (bf16_t)hi.z; r[7] = (bf16_t)hi.w;
    return r;
}

// ---------------- K1: QKV projection as MFMA GEMM -------------------------
// M=NPIX, N=192, K=64.  One wave = one 16-pixel m-tile x one 64-ch n-group.
// B-row permutation: n-tile t, fragment row m -> output channel ngrp*64+m*4+t,
// so after the 4 MFMAs lane m holds 4 CONSECUTIVE channels -> 8-B packed store.
__global__ __launch_bounds__(256) void qkv_kernel(
        const float* __restrict__ x,
        const float* __restrict__ w,
        const float* __restrict__ b,
        __hip_bfloat16* __restrict__ qkv) {
    const int wave  = (blockIdx.x * blockDim.x + threadIdx.x) >> 6;  // 0..6911
    const int ngrp  = wave % 3;          // which 64-channel group of 192
    const int mtile = wave / 3;          // 0..2303
    const int l  = threadIdx.x & 63;
    const int m  = l & 15;
    const int kg = l >> 4;

    const float* xr = x + (size_t)(mtile * 16 + m) * CH + kg * 8;
    const float4 u0 = *(const float4*)(xr);
    const float4 u1 = *(const float4*)(xr + 4);
    const float4 u2 = *(const float4*)(xr + 32);
    const float4 u3 = *(const float4*)(xr + 36);
    const bf16x8 a0 = pack_bf16x8(u0, u1);   // k = 0..31 slice
    const bf16x8 a1 = pack_bf16x8(u2, u3);   // k = 32..63 slice

    const int ch_base = ngrp * 64 + m * 4;            // 4 consecutive channels
    const float4 bias4 = *(const float4*)(b + ch_base);
    const float scale = (ngrp == 0) ? QSCALE : 1.f;   // q group gets 1/sqrt(hd)

    float val[4][4];                                   // [t][r]
    #pragma unroll
    for (int t = 0; t < 4; ++t) {
        const int oc = ngrp * 64 + m * 4 + t;          // permuted B row
        const float* wr_ = w + (size_t)oc * CH + kg * 8;
        const float4 w0 = *(const float4*)(wr_);
        const float4 w1 = *(const float4*)(wr_ + 4);
        const float4 w2 = *(const float4*)(wr_ + 32);
        const float4 w3 = *(const float4*)(wr_ + 36);
        const bf16x8 b0 = pack_bf16x8(w0, w1);
        const bf16x8 b1 = pack_bf16x8(w2, w3);
        f32x4 acc = {0.f, 0.f, 0.f, 0.f};
        acc = __builtin_amdgcn_mfma_f32_16x16x32_bf16(a0, b0, acc, 0, 0, 0);
        acc = __builtin_amdgcn_mfma_f32_16x16x32_bf16(a1, b1, acc, 0, 0, 0);
        const float bias = (t == 0) ? bias4.x : (t == 1) ? bias4.y : (t == 2) ? bias4.z : bias4.w;
        #pragma unroll
        for (int r = 0; r < 4; ++r) val[t][r] = (acc[r] + bias) * scale;
    }

    #pragma unroll
    for (int r = 0; r < 4; ++r) {
        const int pix = mtile * 16 + kg * 4 + r;
        union { ushort4 u; __hip_bfloat16 hh[4]; } pk;
        #pragma unroll
        for (int t = 0; t < 4; ++t) pk.hh[t] = __float2bfloat16(val[t][r]);
        *reinterpret_cast<ushort4*>(qkv + (size_t)pix * QKVC + ch_base) = pk.u;  // 8-B store
    }
}

// ---------------- K2: neighborhood attention, online softmax per k-row ------
// 1 thread = (pixel, head); h is the fastest gid axis so 8 consecutive threads
// read one contiguous 128-B span per neighbor. No score array -> low VGPR.
__global__ __launch_bounds__(256, 6) void attn_kernel(
        const __hip_bfloat16* __restrict__ qkv,
        const float* __restrict__ rpb,
        __hip_bfloat16* __restrict__ aout) {
    const int gid = blockIdx.x * blockDim.x + threadIdx.x;
    const int h = gid & (NH - 1);
    const int pix = gid >> 3;
    const int n = pix / (IH * IW);
    const int rem = pix - n * (IH * IW);
    const int i = rem / IW;
    const int j = rem - i * IW;

    float qv[HD];
    ld8bf(qkv + (size_t)pix * QKVC + h * HD, qv);

    int si = i - 3; si = si < 0 ? 0 : (si > IH - KS ? IH - KS : si);
    int sj = j - 3; sj = sj < 0 ? 0 : (sj > IW - KS ? IW - KS : sj);

    const float* rp = rpb + h * (2 * KS - 1) * (2 * KS - 1)
                    + (sj - j + (KS - 1));             // fold col offset in

    float mrun = -1e30f, lrun = 0.f;
    float acc[HD];
    #pragma unroll
    for (int d = 0; d < HD; ++d) acc[d] = 0.f;

    for (int p = 0; p < KS; ++p) {                     // 7 neighbor rows
        const int ki = si + p;
        const float* rprow = rp + (ki - i + (KS - 1)) * (2 * KS - 1);
        const __hip_bfloat16* row = qkv + ((size_t)(n * IH * IW + ki * IW) + sj) * QKVC + h * HD;

        float s[KS];
        #pragma unroll
        for (int qq = 0; qq < KS; ++qq) {
            float kf[HD];
            ld8bf(row + qq * QKVC + CH, kf);
            float sc = rprow[qq];
            #pragma unroll
            for (int d = 0; d < HD; ++d) sc += qv[d] * kf[d];
            s[qq] = sc;
        }
        float rm = s[0];
        #pragma unroll
        for (int qq = 1; qq < KS; ++qq) rm = fmaxf(rm, s[qq]);
        const float nm = fmaxf(mrun, rm);
        const float alpha = __expf(mrun - nm);
        mrun = nm;
        lrun *= alpha;
        #pragma unroll
        for (int d = 0; d < HD; ++d) acc[d] *= alpha;
        #pragma unroll
        for (int qq = 0; qq < KS; ++qq) {
            const float e = __expf(s[qq] - nm);
            lrun += e;
            float vf[HD];
            ld8bf(row + qq * QKVC + 2 * CH, vf);
            #pragma unroll
            for (int d = 0; d < HD; ++d) acc[d] += e * vf[d];
        }
    }
    const float inv = 1.f / lrun;
    union { uint4 u; __hip_bfloat16 hh[8]; } pk;
    #pragma unroll
    for (int d = 0; d < HD; ++d) pk.hh[d] = __float2bfloat16(acc[d] * inv);
    *reinterpret_cast<uint4*>(aout + (size_t)pix * CH + h * HD) = pk.u;
}

// ---------------- K3: out-projection MFMA + fused LayerNorm -----------------
// Same permuted-B trick: lane m owns channels m*4..m*4+3 -> float4 store and
// float4 bias/gamma/beta loads. LN reduced across the 16 lanes of a kg-group.
__global__ __launch_bounds__(256) void proj_ln_kernel(
        const __hip_bfloat16* __restrict__ aout,
        const float* __restrict__ pw,
        const float* __restrict__ pb,
        const float* __restrict__ g,
        const float* __restrict__ beta,
        float* __restrict__ out) {
    const int mtile = (blockIdx.x * blockDim.x + threadIdx.x) >> 6;  // 0..2303
    const int l  = threadIdx.x & 63;
    const int m  = l & 15;
    const int kg = l >> 4;

    const __hip_bfloat16* ar = aout + (size_t)(mtile * 16 + m) * CH + kg * 8;
    const bf16x8 a0 = *reinterpret_cast<const bf16x8*>(ar);
    const bf16x8 a1 = *reinterpret_cast<const bf16x8*>(ar + 32);

    const int ch_base = m * 4;
    const float4 bias4 = *(const float4*)(pb + ch_base);

    float val[4][4];                                   // [t][r], ch = m*4+t
    #pragma unroll
    for (int t = 0; t < 4; ++t) {
        const int ch = m * 4 + t;                      // permuted B row
        const float* wr_ = pw + (size_t)ch * CH + kg * 8;
        const float4 w0 = *(const float4*)(wr_);
        const float4 w1 = *(const float4*)(wr_ + 4);
        const float4 w2 = *(const float4*)(wr_ + 32);
        const float4 w3 = *(const float4*)(wr_ + 36);
        const bf16x8 b0 = pack_bf16x8(w0, w1);
        const bf16x8 b1 = pack_bf16x8(w2, w3);
        f32x4 acc = {0.f, 0.f, 0.f, 0.f};
        acc = __builtin_amdgcn_mfma_f32_16x16x32_bf16(a0, b0, acc, 0, 0, 0);
        acc = __builtin_amdgcn_mfma_f32_16x16x32_bf16(a1, b1, acc, 0, 0, 0);
        const float bias = (t == 0) ? bias4.x : (t == 1) ? bias4.y : (t == 2) ? bias4.z : bias4.w;
        #pragma unroll
        for (int r = 0; r < 4; ++r) val[t][r] = acc[r] + bias;
    }

    // mean over 64 channels per row (row = kg*4 + r); masks 1,2,4,8 stay in kg-group
    float sm[4];
    #pragma unroll
    for (int r = 0; r < 4; ++r) sm[r] = val[0][r] + val[1][r] + val[2][r] + val[3][r];
    #pragma unroll
    for (int mask = 1; mask <= 8; mask <<= 1) {
        #pragma unroll
        for (int r = 0; r < 4; ++r) sm[r] += __shfl_xor(sm[r], mask, 64);
    }
    float mu[4];
    #pragma unroll
    for (int r = 0; r < 4; ++r) mu[r] = sm[r] * (1.f / 64.f);

    float qs[4];
    #pragma unroll
    for (int r = 0; r < 4; ++r) {
        float a = val[0][r] - mu[r], bq = val[1][r] - mu[r];
        float c = val[2][r] - mu[r], d = val[3][r] - mu[r];
        qs[r] = a * a + bq * bq + c * c + d * d;
    }
    #pragma unroll
    for (int mask = 1; mask <= 8; mask <<= 1) {
        #pragma unroll
        for (int r = 0; r < 4; ++r) qs[r] += __shfl_xor(qs[r], mask, 64);
    }
    float rs[4];
    #pragma unroll
    for (int r = 0; r < 4; ++r) rs[r] = rsqrtf(qs[r] * (1.f / 64.f) + LN_EPS);

    const float4 g4 = *(const float4*)(g + ch_base);
    const float4 be4 = *(const float4*)(beta + ch_base);
    #pragma unroll
    for (int r = 0; r < 4; ++r) {
        const int pix = mtile * 16 + kg * 4 + r;
        float4 o;
        o.x = (val[0][r] - mu[r]) * rs[r] * g4.x + be4.x;
        o.y = (val[1][r] - mu[r]) * rs[r] * g4.y + be4.y;
        o.z = (val[2][r] - mu[r]) * rs[r] * g4.z + be4.z;
        o.w = (val[3][r] - mu[r]) * rs[r] * g4.w + be4.w;
        *reinterpret_cast<float4*>(out + (size_t)pix * CH + ch_base) = o;  // 16-B store
    }
}

extern "C" void kernel_launch(void* const* d_in, const int* in_sizes, int n_in,
                              void* d_out, int out_size, void* d_ws, size_t ws_size,
                              hipStream_t stream) {
    const float* x      = (const float*)d_in[0];
    const float* qkv_w  = (const float*)d_in[1];
    const float* qkv_b  = (const float*)d_in[2];
    const float* proj_w = (const float*)d_in[3];
    const float* proj_b = (const float*)d_in[4];
    const float* rpb    = (const float*)d_in[5];
    const float* ln_g   = (const float*)d_in[6];
    const float* ln_b   = (const float*)d_in[7];
    float* out = (float*)d_out;

    // ws: [qkv bf16: NPIX*192*2 = 14,155,776 B][attn_out bf16: NPIX*64*2 = 4,718,592 B]
    __hip_bfloat16* qkv  = (__hip_bfloat16*)d_ws;
    __hip_bfloat16* aout = (__hip_bfloat16*)((char*)d_ws + (size_t)NPIX * QKVC * 2);

    qkv_kernel<<<1728, 256, 0, stream>>>(x, qkv_w, qkv_b, qkv);      // 6912 waves
    attn_kernel<<<(NPIX * NH) / 256, 256, 0, stream>>>(qkv, rpb, aout);
    proj_ln_kernel<<<576, 256, 0, stream>>>(aout, proj_w, proj_b, ln_g, ln_b, out);
}

// Round 5
// 122.943 us; speedup vs baseline: 3.8078x; 1.1411x over previous
//
#include <hip/hip_runtime.h>
#include <hip/hip_bf16.h>

#define BT   16
#define IH   48
#define IW   48
#define CH   64
#define NH   8
#define HD   8
#define KS   7
#define NPIX (BT*IH*IW)          /* 36864 */
#define QKVC 192
#define LN_EPS 1e-5f
#define QSCALE 0.35355339059327373f

#define TS   8                   /* output tile side (8x8 pixels per block) */
#define HS   14                  /* halo side */
#define HP   (HS*HS)             /* 196 halo pixels */
#define KVS  136                 /* kv LDS row stride in bf16 (128 + 8 pad) */
#define AOS  72                  /* attn-out LDS row stride in bf16 (64 + 8 pad) */

typedef __bf16 bf16_t;
typedef bf16_t bf16x8 __attribute__((ext_vector_type(8)));
typedef float  f32x4  __attribute__((ext_vector_type(4)));

__device__ __forceinline__ float bflo(unsigned u) { union { unsigned i; float f; } v; v.i = u << 16; return v.f; }
__device__ __forceinline__ float bfhi(unsigned u) { union { unsigned i; float f; } v; v.i = u & 0xffff0000u; return v.f; }

__device__ __forceinline__ void ld8bf(const __hip_bfloat16* p, float f[8]) {
    uint4 u = *reinterpret_cast<const uint4*>(p);
    f[0] = bflo(u.x); f[1] = bfhi(u.x);
    f[2] = bflo(u.y); f[3] = bfhi(u.y);
    f[4] = bflo(u.z); f[5] = bfhi(u.z);
    f[6] = bflo(u.w); f[7] = bfhi(u.w);
}

__device__ __forceinline__ bf16x8 pack_bf16x8(float4 lo, float4 hi) {
    bf16x8 r;
    r[0] = (bf16_t)lo.x; r[1] = (bf16_t)lo.y; r[2] = (bf16_t)lo.z; r[3] = (bf16_t)lo.w;
    r[4] = (bf16_t)hi.x; r[5] = (bf16_t)hi.y; r[6] = (bf16_t)hi.z; r[7] = (bf16_t)hi.w;
    return r;
}

// ---------------- K1: QKV projection MFMA GEMM, B-frags register-resident ---
// Wave = (ngrp, 2 m-tiles). B-row permutation: lane m owns channels
// ngrp*64 + m*4 .. +3  -> 8-B packed bf16x4 stores.
__global__ __launch_bounds__(256) void qkv_kernel(
        const float* __restrict__ x,
        const float* __restrict__ w,
        const float* __restrict__ b,
        __hip_bfloat16* __restrict__ qkv) {
    const int gw   = blockIdx.x * 4 + (threadIdx.x >> 6);  // 0..3455
    const int ngrp = gw % 3;
    const int mg   = gw / 3;             // 0..1151 (2 m-tiles each)
    const int l  = threadIdx.x & 63;
    const int m  = l & 15;
    const int kg = l >> 4;

    const int ch_base = ngrp * 64 + m * 4;
    const float4 bias4 = *(const float4*)(b + ch_base);
    const float scale = (ngrp == 0) ? QSCALE : 1.f;   // q gets 1/sqrt(hd)

    bf16x8 wb0[4], wb1[4];               // held across both m-tiles
    #pragma unroll
    for (int t = 0; t < 4; ++t) {
        const float* wr_ = w + (size_t)(ch_base + t) * CH + kg * 8;
        wb0[t] = pack_bf16x8(*(const float4*)(wr_),      *(const float4*)(wr_ + 4));
        wb1[t] = pack_bf16x8(*(const float4*)(wr_ + 32), *(const float4*)(wr_ + 36));
    }

    #pragma unroll
    for (int mm = 0; mm < 2; ++mm) {
        const int mtile = mg * 2 + mm;
        const float* xr = x + (size_t)(mtile * 16 + m) * CH + kg * 8;
        const bf16x8 a0 = pack_bf16x8(*(const float4*)(xr),      *(const float4*)(xr + 4));
        const bf16x8 a1 = pack_bf16x8(*(const float4*)(xr + 32), *(const float4*)(xr + 36));

        float val[4][4];
        #pragma unroll
        for (int t = 0; t < 4; ++t) {
            f32x4 acc = {0.f, 0.f, 0.f, 0.f};
            acc = __builtin_amdgcn_mfma_f32_16x16x32_bf16(a0, wb0[t], acc, 0, 0, 0);
            acc = __builtin_amdgcn_mfma_f32_16x16x32_bf16(a1, wb1[t], acc, 0, 0, 0);
            const float bias = (t == 0) ? bias4.x : (t == 1) ? bias4.y : (t == 2) ? bias4.z : bias4.w;
            #pragma unroll
            for (int r = 0; r < 4; ++r) val[t][r] = (acc[r] + bias) * scale;
        }
        #pragma unroll
        for (int r = 0; r < 4; ++r) {
            const int pix = mtile * 16 + kg * 4 + r;
            union { ushort4 u; __hip_bfloat16 hh[4]; } pk;
            #pragma unroll
            for (int t = 0; t < 4; ++t) pk.hh[t] = __float2bfloat16(val[t][r]);
            *reinterpret_cast<ushort4*>(qkv + (size_t)pix * QKVC + ch_base) = pk.u;
        }
    }
}

// ---------------- K2: fused attention (LDS k/v tile) + proj + LayerNorm -----
// Block = one 8x8 pixel tile of one image. 512 threads.
// Stage k/v halo (14x14) into LDS once; attention reads LDS only; attn-out
// goes to LDS (bf16, MFMA A-layout); waves 0-3 run the 64x64 out-proj MFMA +
// wave-shuffle LayerNorm and store float4 to d_out.
__global__ __launch_bounds__(512) void attn_proj_ln_kernel(
        const __hip_bfloat16* __restrict__ qkv,
        const float* __restrict__ rpb,
        const float* __restrict__ pw,
        const float* __restrict__ pb,
        const float* __restrict__ g,
        const float* __restrict__ beta,
        float* __restrict__ out) {
    __shared__ __hip_bfloat16 kv[HP * KVS];     // 53,312 B
    __shared__ __hip_bfloat16 ao[TS * TS * AOS];// 9,216 B

    const int blk = blockIdx.x;          // 0..575
    const int n   = blk / 36;
    const int t2  = blk % 36;
    const int i0  = (t2 / 6) * TS;
    const int j0  = (t2 % 6) * TS;
    const int tid = threadIdx.x;

    // ---- stage k/v halo: 196 px x 16 chunks of 16B = 3136 chunks ----
    for (int c = tid; c < HP * 16; c += 512) {
        const int px = c >> 4, part = c & 15;
        const int hr = px / HS, hc = px - hr * HS;
        int gr = i0 - 3 + hr; gr = gr < 0 ? 0 : (gr > IH - 1 ? IH - 1 : gr);
        int gc = j0 - 3 + hc; gc = gc < 0 ? 0 : (gc > IW - 1 ? IW - 1 : gc);
        const uint4 v = *reinterpret_cast<const uint4*>(
            qkv + ((size_t)(n * IH * IW + gr * IW + gc)) * QKVC + CH + part * 8);
        *reinterpret_cast<uint4*>(kv + px * KVS + part * 8) = v;
    }
    __syncthreads();

    // ---- attention: 1 thread = (local pixel, head) ----
    {
        const int h  = tid & 7;
        const int pl = tid >> 3;             // 0..63
        const int i  = i0 + (pl >> 3);
        const int j  = j0 + (pl & 7);

        float qv[HD];
        ld8bf(qkv + ((size_t)(n * IH * IW + i * IW + j)) * QKVC + h * HD, qv);

        int si = i - 3; si = si < 0 ? 0 : (si > IH - KS ? IH - KS : si);
        int sj = j - 3; sj = sj < 0 ? 0 : (sj > IW - KS ? IW - KS : sj);
        const float* rp = rpb + h * (2*KS-1) * (2*KS-1) + (sj - j + (KS - 1));
        const int hjb = sj - (j0 - 3);       // halo col of window start

        float mrun = -1e30f, lrun = 0.f;
        float acc[HD];
        #pragma unroll
        for (int d = 0; d < HD; ++d) acc[d] = 0.f;

        for (int p = 0; p < KS; ++p) {
            const int ki = si + p;
            const float* rprow = rp + (ki - i + (KS - 1)) * (2*KS-1);
            const __hip_bfloat16* row = kv + ((ki - (i0 - 3)) * HS + hjb) * KVS + h * HD;

            float s[KS];
            #pragma unroll
            for (int qq = 0; qq < KS; ++qq) {
                float kf[HD];
                ld8bf(row + qq * KVS, kf);
                float sc = rprow[qq];
                #pragma unroll
                for (int d = 0; d < HD; ++d) sc += qv[d] * kf[d];
                s[qq] = sc;
            }
            float rm = s[0];
            #pragma unroll
            for (int qq = 1; qq < KS; ++qq) rm = fmaxf(rm, s[qq]);
            const float nm = fmaxf(mrun, rm);
            const float alpha = __expf(mrun - nm);
            mrun = nm;
            lrun *= alpha;
            #pragma unroll
            for (int d = 0; d < HD; ++d) acc[d] *= alpha;
            #pragma unroll
            for (int qq = 0; qq < KS; ++qq) {
                const float e = __expf(s[qq] - nm);
                lrun += e;
                float vf[HD];
                ld8bf(row + qq * KVS + CH, vf);
                #pragma unroll
                for (int d = 0; d < HD; ++d) acc[d] += e * vf[d];
            }
        }
        const float inv = 1.f / lrun;
        union { uint4 u; __hip_bfloat16 hh[8]; } pk;
        #pragma unroll
        for (int d = 0; d < HD; ++d) pk.hh[d] = __float2bfloat16(acc[d] * inv);
        *reinterpret_cast<uint4*>(ao + pl * AOS + h * HD) = pk.u;
    }
    __syncthreads();

    // ---- proj + LN: waves 0-3, one 16-pixel m-tile each ----
    const int wv = tid >> 6;
    if (wv < 4) {
        const int l  = tid & 63;
        const int m  = l & 15;
        const int kg = l >> 4;

        const __hip_bfloat16* ar = ao + (wv * 16 + m) * AOS + kg * 8;
        const bf16x8 a0 = *reinterpret_cast<const bf16x8*>(ar);
        const bf16x8 a1 = *reinterpret_cast<const bf16x8*>(ar + 32);

        const int ch_base = m * 4;
        const float4 bias4 = *(const float4*)(pb + ch_base);

        float val[4][4];
        #pragma unroll
        for (int t = 0; t < 4; ++t) {
            const float* wr_ = pw + (size_t)(ch_base + t) * CH + kg * 8;  // permuted B row
            const bf16x8 b0 = pack_bf16x8(*(const float4*)(wr_),      *(const float4*)(wr_ + 4));
            const bf16x8 b1 = pack_bf16x8(*(const float4*)(wr_ + 32), *(const float4*)(wr_ + 36));
            f32x4 acc = {0.f, 0.f, 0.f, 0.f};
            acc = __builtin_amdgcn_mfma_f32_16x16x32_bf16(a0, b0, acc, 0, 0, 0);
            acc = __builtin_amdgcn_mfma_f32_16x16x32_bf16(a1, b1, acc, 0, 0, 0);
            const float bias = (t == 0) ? bias4.x : (t == 1) ? bias4.y : (t == 2) ? bias4.z : bias4.w;
            #pragma unroll
            for (int r = 0; r < 4; ++r) val[t][r] = acc[r] + bias;
        }

        float sm[4];
        #pragma unroll
        for (int r = 0; r < 4; ++r) sm[r] = val[0][r] + val[1][r] + val[2][r] + val[3][r];
        #pragma unroll
        for (int mask = 1; mask <= 8; mask <<= 1) {
            #pragma unroll
            for (int r = 0; r < 4; ++r) sm[r] += __shfl_xor(sm[r], mask, 64);
        }
        float mu[4];
        #pragma unroll
        for (int r = 0; r < 4; ++r) mu[r] = sm[r] * (1.f / 64.f);

        float qs[4];
        #pragma unroll
        for (int r = 0; r < 4; ++r) {
            float a = val[0][r] - mu[r], bq = val[1][r] - mu[r];
            float c = val[2][r] - mu[r], d = val[3][r] - mu[r];
            qs[r] = a * a + bq * bq + c * c + d * d;
        }
        #pragma unroll
        for (int mask = 1; mask <= 8; mask <<= 1) {
            #pragma unroll
            for (int r = 0; r < 4; ++r) qs[r] += __shfl_xor(qs[r], mask, 64);
        }
        float rs[4];
        #pragma unroll
        for (int r = 0; r < 4; ++r) rs[r] = rsqrtf(qs[r] * (1.f / 64.f) + LN_EPS);

        const float4 g4  = *(const float4*)(g + ch_base);
        const float4 be4 = *(const float4*)(beta + ch_base);
        #pragma unroll
        for (int r = 0; r < 4; ++r) {
            const int pl = wv * 16 + kg * 4 + r;          // local pixel
            const int gi = i0 + (pl >> 3), gj = j0 + (pl & 7);
            float4 o;
            o.x = (val[0][r] - mu[r]) * rs[r] * g4.x + be4.x;
            o.y = (val[1][r] - mu[r]) * rs[r] * g4.y + be4.y;
            o.z = (val[2][r] - mu[r]) * rs[r] * g4.z + be4.z;
            o.w = (val[3][r] - mu[r]) * rs[r] * g4.w + be4.w;
            *reinterpret_cast<float4*>(out + ((size_t)(n * IH * IW + gi * IW + gj)) * CH + ch_base) = o;
        }
    }
}

extern "C" void kernel_launch(void* const* d_in, const int* in_sizes, int n_in,
                              void* d_out, int out_size, void* d_ws, size_t ws_size,
                              hipStream_t stream) {
    const float* x      = (const float*)d_in[0];
    const float* qkv_w  = (const float*)d_in[1];
    const float* qkv_b  = (const float*)d_in[2];
    const float* proj_w = (const float*)d_in[3];
    const float* proj_b = (const float*)d_in[4];
    const float* rpb    = (const float*)d_in[5];
    const float* ln_g   = (const float*)d_in[6];
    const float* ln_b   = (const float*)d_in[7];
    float* out = (float*)d_out;

    // ws: [qkv bf16: NPIX*192*2 = 14,155,776 B]
    __hip_bfloat16* qkv = (__hip_bfloat16*)d_ws;

    qkv_kernel<<<864, 256, 0, stream>>>(x, qkv_w, qkv_b, qkv);        // 3456 waves
    attn_proj_ln_kernel<<<576, 512, 0, stream>>>(qkv, rpb, proj_w, proj_b,
                                                 ln_g, ln_b, out);    // 1 block / tile
}